// Round 8
// baseline (267.561 us; speedup 1.0000x reference)
//
#include <hip/hip_runtime.h>
#include <math.h>

typedef short bf16x8 __attribute__((ext_vector_type(8)));
typedef float f32x4 __attribute__((ext_vector_type(4)));

#define MFMA_BF16(A,B,C) __builtin_amdgcn_mfma_f32_16x16x32_bf16(A,B,C,0,0,0)

__device__ __forceinline__ unsigned short f2b(float x) {
    union { float f; unsigned int u; } v; v.f = x;
    unsigned int r = v.u + 0x7FFFu + ((v.u >> 16) & 1u);
    return (unsigned short)(r >> 16);
}

// async global->LDS DMA, 16B per lane; LDS dest = wave-uniform base + lane*16
__device__ __forceinline__ void gload16(const unsigned short* g, unsigned short* l) {
    __builtin_amdgcn_global_load_lds(
        (const __attribute__((address_space(1))) unsigned int*)(g),
        (__attribute__((address_space(3))) unsigned int*)(l),
        16, 0, 0);
}
// 4B per lane variant; LDS dest = base + lane*4
__device__ __forceinline__ void gload4(const int* g, int* l) {
    __builtin_amdgcn_global_load_lds(
        (const __attribute__((address_space(1))) unsigned int*)(g),
        (__attribute__((address_space(3))) unsigned int*)(l),
        4, 0, 0);
}

// ---------------------------------------------------------------------------
// fp32 -> bf16 convert (flat)
// ---------------------------------------------------------------------------
__global__ __launch_bounds__(256) void conv_bf16(const float* __restrict__ s,
                                                 unsigned short* __restrict__ d, int n)
{
    int i = blockIdx.x * blockDim.x + threadIdx.x;
    int stride = gridDim.x * blockDim.x;
    for (int idx = i * 4; idx < n; idx += stride * 4) {
        float4 v = *(const float4*)(s + idx);
        ushort4 o;
        o.x = f2b(v.x); o.y = f2b(v.y); o.z = f2b(v.z); o.w = f2b(v.w);
        *(ushort4*)(d + idx) = o;
    }
}

// ---------------------------------------------------------------------------
// Fused weight transpose+convert: Wq|Wk|Wv (fp32, [2048][C]) -> bf16 [C][2048]
// ---------------------------------------------------------------------------
__global__ __launch_bounds__(256) void transp_conv_qkv(const float* __restrict__ Wq,
                                                       const float* __restrict__ Wk,
                                                       const float* __restrict__ Wv,
                                                       unsigned short* __restrict__ dst)
{
    __shared__ float t[32][33];
    const int tx = threadIdx.x, ty = threadIdx.y;   // (32,8)
    int bx = blockIdx.x;
    const float* src; int C, cb, dco;
    if (bx < 32)      { src = Wq; C = 1024; cb = bx;      dco = 0; }
    else if (bx < 40) { src = Wk; C = 256;  cb = bx - 32; dco = 1024; }
    else              { src = Wv; C = 256;  cb = bx - 40; dco = 1280; }
    const int c = cb * 32 + tx;
    const int r0 = blockIdx.y * 32;
#pragma unroll
    for (int i = 0; i < 4; ++i)
        t[ty + i * 8][tx] = src[(size_t)(r0 + ty + i * 8) * C + c];
    __syncthreads();
    const int cc = cb * 32 + ty;
#pragma unroll
    for (int i = 0; i < 4; ++i)
        dst[(size_t)(dco + cc + i * 8) * 2048 + r0 + tx] = f2b(t[tx][ty + i * 8]);
}

__global__ __launch_bounds__(256) void transp_conv(const float* __restrict__ src, int R, int C,
                                                   unsigned short* __restrict__ dst, int pitch)
{
    __shared__ float t[32][33];
    const int tx = threadIdx.x, ty = threadIdx.y;
    const int c = blockIdx.x * 32 + tx;
    const int r0 = blockIdx.y * 32;
#pragma unroll
    for (int i = 0; i < 4; ++i)
        t[ty + i * 8][tx] = src[(size_t)(r0 + ty + i * 8) * C + c];
    __syncthreads();
    const int cc = blockIdx.x * 32 + ty;
#pragma unroll
    for (int i = 0; i < 4; ++i)
        dst[(size_t)(cc + i * 8) * pitch + r0 + tx] = f2b(t[tx][ty + i * 8]);
}

// ---------------------------------------------------------------------------
// bf16 MFMA GEMM, B^T input: C[M][N] = A[M][K] @ Bt[N][K]^T
// BM=128, BN=64, BK=64; 256 threads (4 waves, 2x2); double-buffered
// global_load_lds staging; LDS as pitch-32 sub-tiles (m97 bank geometry).
// MODE 0: fp32 store; MODE 1: fused QKV epilogue.  (unchanged from R7)
// ---------------------------------------------------------------------------
template <int MODE>
__global__ __launch_bounds__(256, 3) void gemm_bt_mfma(
    const unsigned short* __restrict__ A,
    const unsigned short* __restrict__ Bt,
    int M, int N, int K,
    float* __restrict__ Cf,
    unsigned short* __restrict__ qh,
    unsigned short* __restrict__ kh,
    unsigned short* __restrict__ vtt)
{
    __shared__ __align__(16) unsigned short As[2][2 * 128 * 32];   // [buf][kk*4096+row*32+c]
    __shared__ __align__(16) unsigned short Bs[2][2 * 64 * 32];    // [buf][kk*2048+row*32+c]

    const int tid = threadIdx.x;
    const int w = tid >> 6, lane = tid & 63, l15 = lane & 15, quad = lane >> 4;
    const int wm = w & 1, wn = w >> 1;
    const int m0 = blockIdx.y * 128, n0 = blockIdx.x * 64;

    f32x4 acc[4][2];
    const f32x4 zero4 = {0.f, 0.f, 0.f, 0.f};
#pragma unroll
    for (int i = 0; i < 4; ++i)
#pragma unroll
        for (int j = 0; j < 2; ++j) acc[i][j] = zero4;

    const int lrow = lane >> 2, lcol = (lane & 3) * 8;
    const unsigned short* AgL = A  + (size_t)(m0 + w * 32 + lrow) * K + lcol;
    const unsigned short* BgL = Bt + (size_t)(n0 + w * 16 + lrow) * K + lcol;

#pragma unroll
    for (int t = 0; t < 4; ++t) {
        const int sub = t >> 1, half = t & 1;
        gload16(AgL + (size_t)(half * 16) * K + sub * 32,
                &As[0][sub * 4096 + (w * 32 + half * 16) * 32]);
    }
#pragma unroll
    for (int kk = 0; kk < 2; ++kk)
        gload16(BgL + kk * 32, &Bs[0][kk * 2048 + (w * 16) * 32]);
    __syncthreads();

    int cb = 0;
    for (int k0 = 0; k0 < K; k0 += 64) {
        if (k0 + 64 < K) {
            const int nb = cb ^ 1;
#pragma unroll
            for (int t = 0; t < 4; ++t) {
                const int sub = t >> 1, half = t & 1;
                gload16(AgL + (size_t)(half * 16) * K + (k0 + 64) + sub * 32,
                        &As[nb][sub * 4096 + (w * 32 + half * 16) * 32]);
            }
#pragma unroll
            for (int kk = 0; kk < 2; ++kk)
                gload16(BgL + (k0 + 64) + kk * 32, &Bs[nb][kk * 2048 + (w * 16) * 32]);
        }

        bf16x8 af[4][2], bf[2][2];
#pragma unroll
        for (int kk = 0; kk < 2; ++kk) {
#pragma unroll
            for (int mt = 0; mt < 4; ++mt)
                af[mt][kk] = *(const bf16x8*)&As[cb][kk * 4096 + (wm * 64 + mt * 16 + l15) * 32 + quad * 8];
#pragma unroll
            for (int nt = 0; nt < 2; ++nt)
                bf[nt][kk] = *(const bf16x8*)&Bs[cb][kk * 2048 + (wn * 32 + nt * 16 + l15) * 32 + quad * 8];
        }
#pragma unroll
        for (int kk = 0; kk < 2; ++kk)
#pragma unroll
            for (int mt = 0; mt < 4; ++mt)
#pragma unroll
                for (int nt = 0; nt < 2; ++nt)
                    acc[mt][nt] = MFMA_BF16(af[mt][kk], bf[nt][kk], acc[mt][nt]);

        __syncthreads();
        cb ^= 1;
    }

    if (MODE == 0) {
#pragma unroll
        for (int mt = 0; mt < 4; ++mt)
#pragma unroll
            for (int nt = 0; nt < 2; ++nt) {
                const int gn = n0 + wn * 32 + nt * 16 + l15;
#pragma unroll
                for (int r = 0; r < 4; ++r) {
                    const int gm = m0 + wm * 64 + mt * 16 + quad * 4 + r;
                    Cf[(size_t)gm * N + gn] = acc[mt][nt][r];
                }
            }
    } else {
        if (n0 < 1024) {            // Q: tanh -> qh[m][n], pitch 1024
#pragma unroll
            for (int mt = 0; mt < 4; ++mt)
#pragma unroll
                for (int nt = 0; nt < 2; ++nt) {
                    const int gn = n0 + wn * 32 + nt * 16 + l15;
#pragma unroll
                    for (int r = 0; r < 4; ++r) {
                        const int gm = m0 + wm * 64 + mt * 16 + quad * 4 + r;
                        qh[(size_t)gm * 1024 + gn] = f2b(tanhf(acc[mt][nt][r]));
                    }
                }
        } else if (n0 < 1280) {     // K: tanh -> kh[m][n-1024], pitch 256
#pragma unroll
            for (int mt = 0; mt < 4; ++mt)
#pragma unroll
                for (int nt = 0; nt < 2; ++nt) {
                    const int gn = n0 + wn * 32 + nt * 16 + l15 - 1024;
#pragma unroll
                    for (int r = 0; r < 4; ++r) {
                        const int gm = m0 + wm * 64 + mt * 16 + quad * 4 + r;
                        kh[(size_t)gm * 256 + gn] = f2b(tanhf(acc[mt][nt][r]));
                    }
                }
        } else {                    // V: sigmoid -> vtt[(b*4+g)*64+v][s]
#pragma unroll
            for (int mt = 0; mt < 4; ++mt)
#pragma unroll
                for (int nt = 0; nt < 2; ++nt) {
                    const int gn = n0 + wn * 32 + nt * 16 + l15 - 1280;
                    const int g = gn >> 6, vv = gn & 63;
                    const int s0 = m0 + wm * 64 + mt * 16 + quad * 4;
                    const int b = s0 >> 11, sl = s0 & 2047;
                    ushort4 pk;
                    unsigned short* pp = (unsigned short*)&pk;
#pragma unroll
                    for (int r = 0; r < 4; ++r) {
                        float sv = 1.0f / (1.0f + __expf(-acc[mt][nt][r]));
                        pp[r] = f2b(sv);
                    }
                    *(ushort4*)&vtt[((size_t)(b * 4 + g) * 64 + vv) * 2048 + sl] = pk;
                }
        }
    }
}

// ---------------------------------------------------------------------------
// MFMA flash attention, fixed-max softmax, DMA-staged double-buffered K/V.
// Block = (qt, h, b), ONE q-tile of 64 rows (qt descending for causal
// balance; grid 1024 -> 3 blocks/CU). Wave w owns q-rows q0+w*16..+15.
// K/V/mask staged via global_load_lds into unpadded pitch-32 sub-tiles
// (same geometry as the GEMM); tile k+1's DMA issued before computing
// tile k; one barrier per tile.
// Scores bounded (|s|<1) -> p = exp2(s*log2e/64), no running max/alpha;
// per-lane psum, one reduction at the end.
// S^T = K.Q^T: lane q=l15, j=quad*4+r -> packed ushort4 P^T store to
// per-wave Ps (pitch 72 to spread b64-write banks); PV A-frag ds_read_b128.
// ---------------------------------------------------------------------------
__global__ __launch_bounds__(256, 3) void rosa_attn_mfma(
    const unsigned short* __restrict__ qh,
    const unsigned short* __restrict__ kh,
    const unsigned short* __restrict__ vtt,
    const int* __restrict__ amask,
    const float* __restrict__ emb0,
    const float* __restrict__ emb1,
    unsigned short* __restrict__ ob)
{
    __shared__ __align__(16) unsigned short Ks[2][2][64 * 32];  // [buf][kk][row*32+c] 16KB
    __shared__ __align__(16) unsigned short Vs[2][2][64 * 32];  // [buf][kk][v*32+j]   16KB
    __shared__ __align__(16) unsigned short Ps[4][16][72];      // [wave][q][j]        9.2KB
    __shared__ int Mski[2][64];

    const int qt = 31 - blockIdx.x;               // descending: big blocks first
    const int h = blockIdx.y, b = blockIdx.z, g = h >> 2;
    const int tid = threadIdx.x;
    const int w = tid >> 6, lane = tid & 63, l15 = lane & 15, quad = lane >> 4;

    const int q0 = qt * 64;
    const int nkt = qt + 1;
    const int qg = q0 + w * 16 + l15;

    // DMA lane geometry: row = lane>>2 (16 rows/issue), col = (lane&3)*8
    const int lrow = lane >> 2, lcol = (lane & 3) * 8;
    const unsigned short* kbase = kh + (size_t)b * 2048 * 256 + g * 64;     // row stride 256
    const unsigned short* vbase = vtt + ((size_t)(b * 4 + g) * 64) * 2048;  // row stride 2048
    const int* mbase = amask + b * 2048;

    // Q B-fragment (n = q = l15, k = d), per wave, from global (L2-hot)
    const unsigned short* qrow = qh + ((size_t)(b * 2048 + q0 + w * 16 + l15) * 16 + h) * 64;
    const bf16x8 qf0 = *(const bf16x8*)(qrow + quad * 8);
    const bf16x8 qf1 = *(const bf16x8*)(qrow + 32 + quad * 8);

    const f32x4 zero4 = {0.f, 0.f, 0.f, 0.f};
    const float cexp = 0.0225421100f;             // log2(e)/64

    f32x4 oacc[4];
#pragma unroll
    for (int t = 0; t < 4; ++t) oacc[t] = zero4;
    float psum = 0.0f;

    // wave w stages K rows w*16..+15 and V rows w*16..+15, both kk halves
#define STAGE_TILE(k0s, buf)                                                          \
    {                                                                                 \
        _Pragma("unroll")                                                             \
        for (int kk = 0; kk < 2; ++kk) {                                              \
            gload16(kbase + (size_t)((k0s) + w * 16 + lrow) * 256 + kk * 32 + lcol,   \
                    &Ks[buf][kk][(w * 16) * 32]);                                     \
            gload16(vbase + (size_t)(w * 16 + lrow) * 2048 + (k0s) + kk * 32 + lcol,  \
                    &Vs[buf][kk][(w * 16) * 32]);                                     \
        }                                                                             \
        if (w == 0) gload4(mbase + (k0s) + lane, &Mski[buf][0]);                      \
    }

    // prologue: stage tile 0 into buffer 0
    STAGE_TILE(0, 0)
    __syncthreads();                              // vmcnt(0) drain

    int cb = 0;
    for (int kt = 0; kt < nkt; ++kt) {
        if (kt + 1 < nkt) STAGE_TILE((kt + 1) * 64, cb ^ 1)

        const int k0 = kt * 64;
        const bool diag = (kt == qt);
        const int ntlim = diag ? (w + 1) : 4;

        // S^T = K.Q^T per 16x16 sub-tile; fixed-max softmax; pack P^T
#pragma unroll
        for (int nt = 0; nt < 4; ++nt) {
            ushort4 pk;
            if (nt < ntlim) {
                bf16x8 kf0 = *(const bf16x8*)&Ks[cb][0][(nt * 16 + l15) * 32 + quad * 8];
                bf16x8 kf1 = *(const bf16x8*)&Ks[cb][1][(nt * 16 + l15) * 32 + quad * 8];
                f32x4 sc = MFMA_BF16(kf0, qf0, zero4);
                sc = MFMA_BF16(kf1, qf1, sc);
                const int4 m4 = *(const int4*)&Mski[cb][nt * 16 + quad * 4];
                const int* mm = (const int*)&m4;
                unsigned short* pp = (unsigned short*)&pk;
#pragma unroll
                for (int r = 0; r < 4; ++r) {
                    float p = __builtin_exp2f(sc[r] * cexp);
                    bool valid = (mm[r] != 0);
                    if (diag) valid = valid && ((k0 + nt * 16 + quad * 4 + r) <= qg);
                    p = valid ? p : 0.0f;
                    psum += p;
                    pp[r] = f2b(p);
                }
            } else {
                pk.x = 0; pk.y = 0; pk.z = 0; pk.w = 0;
            }
            *(ushort4*)&Ps[w][l15][nt * 16 + quad * 4] = pk;   // P^T packed along j
        }

        // O += P.V (in-wave DS ordering covers Ps write->read)
        const bf16x8 pf0 = *(const bf16x8*)&Ps[w][l15][quad * 8];
        const bf16x8 pf1 = *(const bf16x8*)&Ps[w][l15][32 + quad * 8];
#pragma unroll
        for (int nt = 0; nt < 4; ++nt) {
            bf16x8 vf0 = *(const bf16x8*)&Vs[cb][0][(nt * 16 + l15) * 32 + quad * 8];
            bf16x8 vf1 = *(const bf16x8*)&Vs[cb][1][(nt * 16 + l15) * 32 + quad * 8];
            oacc[nt] = MFMA_BF16(pf0, vf0, oacc[nt]);
            oacc[nt] = MFMA_BF16(pf1, vf1, oacc[nt]);
        }

        if (kt + 1 < nkt) {
            __syncthreads();   // drains next tile's DMA + all waves' cb reads
            cb ^= 1;
        }
    }
#undef STAGE_TILE

    // l reduction: sum partials across the 4 quads holding the same q
    float l = psum;
    l += __shfl_xor(l, 16);
    l += __shfl_xor(l, 32);
    float lq[4];
#pragma unroll
    for (int r = 0; r < 4; ++r) lq[r] = __shfl(l, quad * 4 + r);

    // epilogue: oacc row = q_local = quad*4+r, col = v = nt*16+l15
#pragma unroll
    for (int nt = 0; nt < 4; ++nt) {
        const float e0 = emb0[h * 64 + nt * 16 + l15];
        const float e1 = emb1[h * 64 + nt * 16 + l15];
#pragma unroll
        for (int r = 0; r < 4; ++r) {
            const float ctx = oacc[nt][r] / lq[r];
            const float val = e0 + ctx * (e1 - e0);
            const size_t s_idx = (size_t)(b * 2048 + q0 + w * 16 + quad * 4 + r);
            ob[(s_idx * 16 + h) * 64 + nt * 16 + l15] = f2b(val);
        }
    }
}

// ---------------------------------------------------------------------------
extern "C" void kernel_launch(void* const* d_in, const int* in_sizes, int n_in,
                              void* d_out, int out_size, void* d_ws, size_t ws_size,
                              hipStream_t stream)
{
    const float* x    = (const float*)d_in[0];
    const int*   amask= (const int*)d_in[1];
    const float* Wq   = (const float*)d_in[2];
    const float* Wk   = (const float*)d_in[3];
    const float* Wv   = (const float*)d_in[4];
    const float* Wo   = (const float*)d_in[5];
    const float* emb0 = (const float*)d_in[6];
    const float* emb1 = (const float*)d_in[7];
    float* out = (float*)d_out;

    char* base = (char*)d_ws;
    unsigned short* xh    = (unsigned short*)(base);                      // 16 MB
    unsigned short* ob    = xh;                                           // aliases xh
    unsigned short* Wqkvt = (unsigned short*)(base + (16u << 20));        // 6 MB
    unsigned short* Wot   = (unsigned short*)(base + (22u << 20));        // 4 MB
    unsigned short* qh    = (unsigned short*)(base + (26u << 20));        // 8 MB
    unsigned short* kh    = (unsigned short*)(base + (34u << 20));        // 2 MB
    unsigned short* vtt   = (unsigned short*)(base + (36u << 20));        // 2 MB

    conv_bf16<<<2048, 256, 0, stream>>>(x, xh, 4096 * 2048);
    transp_conv_qkv<<<dim3(48, 64), dim3(32, 8), 0, stream>>>(Wq, Wk, Wv, Wqkvt);
    transp_conv<<<dim3(64, 32), dim3(32, 8), 0, stream>>>(Wo, 1024, 2048, Wot, 1024);

    gemm_bt_mfma<1><<<dim3(24, 32), 256, 0, stream>>>(xh, Wqkvt, 4096, 1536, 2048,
                                                      nullptr, qh, kh, vtt);
    rosa_attn_mfma<<<dim3(32, 16, 2), 256, 0, stream>>>(qh, kh, vtt, amask, emb0, emb1, ob);
    gemm_bt_mfma<0><<<dim3(32, 32), 256, 0, stream>>>(ob, Wot, 4096, 2048, 1024,
                                                      out, nullptr, nullptr, nullptr);
}

// Round 9
// 234.721 us; speedup vs baseline: 1.1399x; 1.1399x over previous
//
#include <hip/hip_runtime.h>
#include <math.h>

typedef short bf16x8 __attribute__((ext_vector_type(8)));
typedef float f32x4 __attribute__((ext_vector_type(4)));

#define MFMA_BF16(A,B,C) __builtin_amdgcn_mfma_f32_16x16x32_bf16(A,B,C,0,0,0)

__device__ __forceinline__ unsigned short f2b(float x) {
    union { float f; unsigned int u; } v; v.f = x;
    unsigned int r = v.u + 0x7FFFu + ((v.u >> 16) & 1u);
    return (unsigned short)(r >> 16);
}

// async global->LDS DMA, 16B per lane; LDS dest = wave-uniform base + lane*16
__device__ __forceinline__ void gload16(const unsigned short* g, unsigned short* l) {
    __builtin_amdgcn_global_load_lds(
        (const __attribute__((address_space(1))) unsigned int*)(g),
        (__attribute__((address_space(3))) unsigned int*)(l),
        16, 0, 0);
}
// 4B per lane variant; LDS dest = base + lane*4
__device__ __forceinline__ void gload4(const int* g, int* l) {
    __builtin_amdgcn_global_load_lds(
        (const __attribute__((address_space(1))) unsigned int*)(g),
        (__attribute__((address_space(3))) unsigned int*)(l),
        4, 0, 0);
}

// ---------------------------------------------------------------------------
// fp32 -> bf16 convert (flat)
// ---------------------------------------------------------------------------
__global__ __launch_bounds__(256) void conv_bf16(const float* __restrict__ s,
                                                 unsigned short* __restrict__ d, int n)
{
    int i = blockIdx.x * blockDim.x + threadIdx.x;
    int stride = gridDim.x * blockDim.x;
    for (int idx = i * 4; idx < n; idx += stride * 4) {
        float4 v = *(const float4*)(s + idx);
        ushort4 o;
        o.x = f2b(v.x); o.y = f2b(v.y); o.z = f2b(v.z); o.w = f2b(v.w);
        *(ushort4*)(d + idx) = o;
    }
}

// ---------------------------------------------------------------------------
// Fused weight transpose+convert: Wq|Wk|Wv (fp32, [2048][C]) -> bf16 [C][2048]
// ---------------------------------------------------------------------------
__global__ __launch_bounds__(256) void transp_conv_qkv(const float* __restrict__ Wq,
                                                       const float* __restrict__ Wk,
                                                       const float* __restrict__ Wv,
                                                       unsigned short* __restrict__ dst)
{
    __shared__ float t[32][33];
    const int tx = threadIdx.x, ty = threadIdx.y;   // (32,8)
    int bx = blockIdx.x;
    const float* src; int C, cb, dco;
    if (bx < 32)      { src = Wq; C = 1024; cb = bx;      dco = 0; }
    else if (bx < 40) { src = Wk; C = 256;  cb = bx - 32; dco = 1024; }
    else              { src = Wv; C = 256;  cb = bx - 40; dco = 1280; }
    const int c = cb * 32 + tx;
    const int r0 = blockIdx.y * 32;
#pragma unroll
    for (int i = 0; i < 4; ++i)
        t[ty + i * 8][tx] = src[(size_t)(r0 + ty + i * 8) * C + c];
    __syncthreads();
    const int cc = cb * 32 + ty;
#pragma unroll
    for (int i = 0; i < 4; ++i)
        dst[(size_t)(dco + cc + i * 8) * 2048 + r0 + tx] = f2b(t[tx][ty + i * 8]);
}

__global__ __launch_bounds__(256) void transp_conv(const float* __restrict__ src, int R, int C,
                                                   unsigned short* __restrict__ dst, int pitch)
{
    __shared__ float t[32][33];
    const int tx = threadIdx.x, ty = threadIdx.y;
    const int c = blockIdx.x * 32 + tx;
    const int r0 = blockIdx.y * 32;
#pragma unroll
    for (int i = 0; i < 4; ++i)
        t[ty + i * 8][tx] = src[(size_t)(r0 + ty + i * 8) * C + c];
    __syncthreads();
    const int cc = blockIdx.x * 32 + ty;
#pragma unroll
    for (int i = 0; i < 4; ++i)
        dst[(size_t)(cc + i * 8) * pitch + r0 + tx] = f2b(t[tx][ty + i * 8]);
}

// ---------------------------------------------------------------------------
// bf16 MFMA GEMM, B^T input: C[M][N] = A[M][K] @ Bt[N][K]^T
// BM=128, BN=64, BK=64; 256 threads (4 waves, 2x2); double-buffered
// global_load_lds staging; LDS as pitch-32 sub-tiles.  (unchanged from R7)
// ---------------------------------------------------------------------------
template <int MODE>
__global__ __launch_bounds__(256, 3) void gemm_bt_mfma(
    const unsigned short* __restrict__ A,
    const unsigned short* __restrict__ Bt,
    int M, int N, int K,
    float* __restrict__ Cf,
    unsigned short* __restrict__ qh,
    unsigned short* __restrict__ kh,
    unsigned short* __restrict__ vtt)
{
    __shared__ __align__(16) unsigned short As[2][2 * 128 * 32];
    __shared__ __align__(16) unsigned short Bs[2][2 * 64 * 32];

    const int tid = threadIdx.x;
    const int w = tid >> 6, lane = tid & 63, l15 = lane & 15, quad = lane >> 4;
    const int wm = w & 1, wn = w >> 1;
    const int m0 = blockIdx.y * 128, n0 = blockIdx.x * 64;

    f32x4 acc[4][2];
    const f32x4 zero4 = {0.f, 0.f, 0.f, 0.f};
#pragma unroll
    for (int i = 0; i < 4; ++i)
#pragma unroll
        for (int j = 0; j < 2; ++j) acc[i][j] = zero4;

    const int lrow = lane >> 2, lcol = (lane & 3) * 8;
    const unsigned short* AgL = A  + (size_t)(m0 + w * 32 + lrow) * K + lcol;
    const unsigned short* BgL = Bt + (size_t)(n0 + w * 16 + lrow) * K + lcol;

#pragma unroll
    for (int t = 0; t < 4; ++t) {
        const int sub = t >> 1, half = t & 1;
        gload16(AgL + (size_t)(half * 16) * K + sub * 32,
                &As[0][sub * 4096 + (w * 32 + half * 16) * 32]);
    }
#pragma unroll
    for (int kk = 0; kk < 2; ++kk)
        gload16(BgL + kk * 32, &Bs[0][kk * 2048 + (w * 16) * 32]);
    __syncthreads();

    int cb = 0;
    for (int k0 = 0; k0 < K; k0 += 64) {
        if (k0 + 64 < K) {
            const int nb = cb ^ 1;
#pragma unroll
            for (int t = 0; t < 4; ++t) {
                const int sub = t >> 1, half = t & 1;
                gload16(AgL + (size_t)(half * 16) * K + (k0 + 64) + sub * 32,
                        &As[nb][sub * 4096 + (w * 32 + half * 16) * 32]);
            }
#pragma unroll
            for (int kk = 0; kk < 2; ++kk)
                gload16(BgL + (k0 + 64) + kk * 32, &Bs[nb][kk * 2048 + (w * 16) * 32]);
        }

        bf16x8 af[4][2], bf[2][2];
#pragma unroll
        for (int kk = 0; kk < 2; ++kk) {
#pragma unroll
            for (int mt = 0; mt < 4; ++mt)
                af[mt][kk] = *(const bf16x8*)&As[cb][kk * 4096 + (wm * 64 + mt * 16 + l15) * 32 + quad * 8];
#pragma unroll
            for (int nt = 0; nt < 2; ++nt)
                bf[nt][kk] = *(const bf16x8*)&Bs[cb][kk * 2048 + (wn * 32 + nt * 16 + l15) * 32 + quad * 8];
        }
#pragma unroll
        for (int kk = 0; kk < 2; ++kk)
#pragma unroll
            for (int mt = 0; mt < 4; ++mt)
#pragma unroll
                for (int nt = 0; nt < 2; ++nt)
                    acc[mt][nt] = MFMA_BF16(af[mt][kk], bf[nt][kk], acc[mt][nt]);

        __syncthreads();
        cb ^= 1;
    }

    if (MODE == 0) {
#pragma unroll
        for (int mt = 0; mt < 4; ++mt)
#pragma unroll
            for (int nt = 0; nt < 2; ++nt) {
                const int gn = n0 + wn * 32 + nt * 16 + l15;
#pragma unroll
                for (int r = 0; r < 4; ++r) {
                    const int gm = m0 + wm * 64 + mt * 16 + quad * 4 + r;
                    Cf[(size_t)gm * N + gn] = acc[mt][nt][r];
                }
            }
    } else {
        if (n0 < 1024) {            // Q: tanh -> qh[m][n], pitch 1024
#pragma unroll
            for (int mt = 0; mt < 4; ++mt)
#pragma unroll
                for (int nt = 0; nt < 2; ++nt) {
                    const int gn = n0 + wn * 32 + nt * 16 + l15;
#pragma unroll
                    for (int r = 0; r < 4; ++r) {
                        const int gm = m0 + wm * 64 + mt * 16 + quad * 4 + r;
                        qh[(size_t)gm * 1024 + gn] = f2b(tanhf(acc[mt][nt][r]));
                    }
                }
        } else if (n0 < 1280) {     // K: tanh -> kh[m][n-1024], pitch 256
#pragma unroll
            for (int mt = 0; mt < 4; ++mt)
#pragma unroll
                for (int nt = 0; nt < 2; ++nt) {
                    const int gn = n0 + wn * 32 + nt * 16 + l15 - 1024;
#pragma unroll
                    for (int r = 0; r < 4; ++r) {
                        const int gm = m0 + wm * 64 + mt * 16 + quad * 4 + r;
                        kh[(size_t)gm * 256 + gn] = f2b(tanhf(acc[mt][nt][r]));
                    }
                }
        } else {                    // V: sigmoid -> vtt[(b*4+g)*64+v][s]
#pragma unroll
            for (int mt = 0; mt < 4; ++mt)
#pragma unroll
                for (int nt = 0; nt < 2; ++nt) {
                    const int gn = n0 + wn * 32 + nt * 16 + l15 - 1280;
                    const int g = gn >> 6, vv = gn & 63;
                    const int s0 = m0 + wm * 64 + mt * 16 + quad * 4;
                    const int b = s0 >> 11, sl = s0 & 2047;
                    ushort4 pk;
                    unsigned short* pp = (unsigned short*)&pk;
#pragma unroll
                    for (int r = 0; r < 4; ++r) {
                        float sv = 1.0f / (1.0f + __expf(-acc[mt][nt][r]));
                        pp[r] = f2b(sv);
                    }
                    *(ushort4*)&vtt[((size_t)(b * 4 + g) * 64 + vv) * 2048 + sl] = pk;
                }
        }
    }
}

// ---------------------------------------------------------------------------
// MFMA flash attention: R7's PAIRED structure (block = (pair,h,b), q-tiles
// qt and 31-qt -> uniform 33 k-tiles/block, grid 512 = 2 equal blocks/CU)
// + R8's DMA staging (global_load_lds into pitch-32 sub-tiles, no register
// round-trip). One barrier/tile. Fixed-max softmax (|s|<1).
// ---------------------------------------------------------------------------
__global__ __launch_bounds__(256) void rosa_attn_mfma(
    const unsigned short* __restrict__ qh,
    const unsigned short* __restrict__ kh,
    const unsigned short* __restrict__ vtt,
    const int* __restrict__ amask,
    const float* __restrict__ emb0,
    const float* __restrict__ emb1,
    unsigned short* __restrict__ ob)
{
    __shared__ __align__(16) unsigned short Ks[2][2][64 * 32];  // [buf][kk][row*32+c]
    __shared__ __align__(16) unsigned short Vs[2][2][64 * 32];  // [buf][kk][v*32+j]
    __shared__ __align__(16) unsigned short Ps[4][16][72];      // [wave][q][j]
    __shared__ int Mski[2][64];

    const int pairI = blockIdx.x;                 // 0..15
    const int h = blockIdx.y, b = blockIdx.z, g = h >> 2;
    const int tid = threadIdx.x;
    const int w = tid >> 6, lane = tid & 63, l15 = lane & 15, quad = lane >> 4;

    // DMA lane geometry: row = lane>>2 (16 rows/issue), col = (lane&3)*8
    const int lrow = lane >> 2, lcol = (lane & 3) * 8;
    const unsigned short* kst = kh + (size_t)b * 2048 * 256 + g * 64
                               + (size_t)(w * 16 + lrow) * 256 + lcol;   // + k0*256 + kk*32
    const unsigned short* vst = vtt + ((size_t)(b * 4 + g) * 64) * 2048
                               + (size_t)(w * 16 + lrow) * 2048 + lcol;  // + k0 + kk*32
    const int* mbase = amask + b * 2048;

    const f32x4 zero4 = {0.f, 0.f, 0.f, 0.f};
    const float cexp = 0.0225421100f;             // log2(e)/64

    // wave w stages K rows w*16..+15 and V rows w*16..+15, both kk halves
#define STAGE_TILE(k0s, buf)                                              \
    {                                                                     \
        gload16(kst + (size_t)(k0s) * 256,      &Ks[buf][0][(w * 16) * 32]); \
        gload16(kst + (size_t)(k0s) * 256 + 32, &Ks[buf][1][(w * 16) * 32]); \
        gload16(vst + (k0s),                    &Vs[buf][0][(w * 16) * 32]); \
        gload16(vst + (k0s) + 32,               &Vs[buf][1][(w * 16) * 32]); \
        if (w == 0) gload4(mbase + (k0s) + lane, &Mski[buf][0]);          \
    }

    for (int half = 0; half < 2; ++half) {
        const int qt = (half == 0) ? pairI : 31 - pairI;
        const int q0 = qt * 64;
        const int nkt = qt + 1;
        const int qg = q0 + w * 16 + l15;

        // Q B-fragment (n = q = l15, k = d), per wave, from global (L2-hot)
        const unsigned short* qrow = qh + ((size_t)(b * 2048 + q0 + w * 16 + l15) * 16 + h) * 64;
        const bf16x8 qf0 = *(const bf16x8*)(qrow + quad * 8);
        const bf16x8 qf1 = *(const bf16x8*)(qrow + 32 + quad * 8);

        f32x4 oacc[4];
#pragma unroll
        for (int t = 0; t < 4; ++t) oacc[t] = zero4;
        float psum = 0.0f;

        __syncthreads();           // protect bufs from previous half's readers
        STAGE_TILE(0, 0)
        __syncthreads();           // vmcnt(0) drain: tile 0 visible

        int cb = 0;
        for (int kt = 0; kt < nkt; ++kt) {
            if (kt + 1 < nkt) STAGE_TILE((kt + 1) * 64, cb ^ 1)

            const int k0 = kt * 64;
            const bool diag = (kt == qt);
            const int ntlim = diag ? (w + 1) : 4;

            // S^T = K.Q^T per 16x16 sub-tile; fixed-max softmax; pack P^T
#pragma unroll
            for (int nt = 0; nt < 4; ++nt) {
                ushort4 pk;
                if (nt < ntlim) {
                    bf16x8 kf0 = *(const bf16x8*)&Ks[cb][0][(nt * 16 + l15) * 32 + quad * 8];
                    bf16x8 kf1 = *(const bf16x8*)&Ks[cb][1][(nt * 16 + l15) * 32 + quad * 8];
                    f32x4 sc = MFMA_BF16(kf0, qf0, zero4);
                    sc = MFMA_BF16(kf1, qf1, sc);
                    const int4 m4 = *(const int4*)&Mski[cb][nt * 16 + quad * 4];
                    const int* mm = (const int*)&m4;
                    unsigned short* pp = (unsigned short*)&pk;
#pragma unroll
                    for (int r = 0; r < 4; ++r) {
                        float p = __builtin_exp2f(sc[r] * cexp);
                        bool valid = (mm[r] != 0);
                        if (diag) valid = valid && ((k0 + nt * 16 + quad * 4 + r) <= qg);
                        p = valid ? p : 0.0f;
                        psum += p;
                        pp[r] = f2b(p);
                    }
                } else {
                    pk.x = 0; pk.y = 0; pk.z = 0; pk.w = 0;
                }
                *(ushort4*)&Ps[w][l15][nt * 16 + quad * 4] = pk;   // P^T packed along j
            }

            // O += P.V (in-wave DS ordering covers Ps write->read)
            const bf16x8 pf0 = *(const bf16x8*)&Ps[w][l15][quad * 8];
            const bf16x8 pf1 = *(const bf16x8*)&Ps[w][l15][32 + quad * 8];
#pragma unroll
            for (int nt = 0; nt < 4; ++nt) {
                bf16x8 vf0 = *(const bf16x8*)&Vs[cb][0][(nt * 16 + l15) * 32 + quad * 8];
                bf16x8 vf1 = *(const bf16x8*)&Vs[cb][1][(nt * 16 + l15) * 32 + quad * 8];
                oacc[nt] = MFMA_BF16(pf0, vf0, oacc[nt]);
                oacc[nt] = MFMA_BF16(pf1, vf1, oacc[nt]);
            }

            if (kt + 1 < nkt) {
                __syncthreads();   // drains next tile's DMA + all waves' cb reads
                cb ^= 1;
            }
        }

        // l reduction: sum partials across the 4 quads holding the same q
        float l = psum;
        l += __shfl_xor(l, 16);
        l += __shfl_xor(l, 32);
        float lq[4];
#pragma unroll
        for (int r = 0; r < 4; ++r) lq[r] = __shfl(l, quad * 4 + r);

        // epilogue: oacc row = q_local = quad*4+r, col = v = nt*16+l15
#pragma unroll
        for (int nt = 0; nt < 4; ++nt) {
            const float e0 = emb0[h * 64 + nt * 16 + l15];
            const float e1 = emb1[h * 64 + nt * 16 + l15];
#pragma unroll
            for (int r = 0; r < 4; ++r) {
                const float ctx = oacc[nt][r] / lq[r];
                const float val = e0 + ctx * (e1 - e0);
                const size_t s_idx = (size_t)(b * 2048 + q0 + w * 16 + quad * 4 + r);
                ob[(s_idx * 16 + h) * 64 + nt * 16 + l15] = f2b(val);
            }
        }
    }
#undef STAGE_TILE
}

// ---------------------------------------------------------------------------
extern "C" void kernel_launch(void* const* d_in, const int* in_sizes, int n_in,
                              void* d_out, int out_size, void* d_ws, size_t ws_size,
                              hipStream_t stream)
{
    const float* x    = (const float*)d_in[0];
    const int*   amask= (const int*)d_in[1];
    const float* Wq   = (const float*)d_in[2];
    const float* Wk   = (const float*)d_in[3];
    const float* Wv   = (const float*)d_in[4];
    const float* Wo   = (const float*)d_in[5];
    const float* emb0 = (const float*)d_in[6];
    const float* emb1 = (const float*)d_in[7];
    float* out = (float*)d_out;

    char* base = (char*)d_ws;
    unsigned short* xh    = (unsigned short*)(base);                      // 16 MB
    unsigned short* ob    = xh;                                           // aliases xh
    unsigned short* Wqkvt = (unsigned short*)(base + (16u << 20));        // 6 MB
    unsigned short* Wot   = (unsigned short*)(base + (22u << 20));        // 4 MB
    unsigned short* qh    = (unsigned short*)(base + (26u << 20));        // 8 MB
    unsigned short* kh    = (unsigned short*)(base + (34u << 20));        // 2 MB
    unsigned short* vtt   = (unsigned short*)(base + (36u << 20));        // 2 MB

    conv_bf16<<<2048, 256, 0, stream>>>(x, xh, 4096 * 2048);
    transp_conv_qkv<<<dim3(48, 64), dim3(32, 8), 0, stream>>>(Wq, Wk, Wv, Wqkvt);
    transp_conv<<<dim3(64, 32), dim3(32, 8), 0, stream>>>(Wo, 1024, 2048, Wot, 1024);

    gemm_bt_mfma<1><<<dim3(24, 32), 256, 0, stream>>>(xh, Wqkvt, 4096, 1536, 2048,
                                                      nullptr, qh, kh, vtt);
    rosa_attn_mfma<<<dim3(16, 16, 2), 256, 0, stream>>>(qh, kh, vtt, amask, emb0, emb1, ob);
    gemm_bt_mfma<0><<<dim3(32, 32), 256, 0, stream>>>(ob, Wot, 4096, 2048, 1024,
                                                      out, nullptr, nullptr, nullptr);
}